// Round 11
// baseline (126.820 us; speedup 1.0000x reference)
//
#include <hip/hip_runtime.h>

typedef short bf16x8 __attribute__((ext_vector_type(8)));
typedef float f32x4 __attribute__((ext_vector_type(4)));

static __device__ __forceinline__ unsigned short f2bf(float f) {
  unsigned u = __builtin_bit_cast(unsigned, f);
  u += 0x7FFFu + ((u >> 16) & 1u);   // round-nearest-even to bf16
  return (unsigned short)(u >> 16);
}

static __device__ __forceinline__ bf16x8 pack8s(const float* p, float s) {
  float4 a = *(const float4*)p;
  float4 b = *(const float4*)(p + 4);
  bf16x8 r;
  r[0] = (short)f2bf(a.x * s); r[1] = (short)f2bf(a.y * s);
  r[2] = (short)f2bf(a.z * s); r[3] = (short)f2bf(a.w * s);
  r[4] = (short)f2bf(b.x * s); r[5] = (short)f2bf(b.y * s);
  r[6] = (short)f2bf(b.z * s); r[7] = (short)f2bf(b.w * s);
  return r;
}

#define NLOG2E -1.442695040888963f
#define N2LOG2E -2.885390081777927f

// ---------------- pw f32[128][512] -> bf16 (one-time) ----------------
__global__ __launch_bounds__(512) void pwprep_kernel(
    const float* __restrict__ pw, unsigned short* __restrict__ pwb) {
  const int i = blockIdx.x * 512 + threadIdx.x;
  pwb[i] = f2bf(pw[i]);
}

// ---------------- LayerNorm: x[B,C,H,W] f32 -> xn[B,HW,C] bf16 ----------------
__global__ __launch_bounds__(512, 2) void ln_kernel(
    const float* __restrict__ x, const float* __restrict__ lg,
    const float* __restrict__ lb, unsigned short* __restrict__ xn) {
  __shared__ __align__(16) unsigned char slds[35840];
  float* mu_s = (float*)(slds + 34816);
  float* rs_s = (float*)(slds + 35328);
  const int tid = threadIdx.x;
  const int bid = blockIdx.x;
  const int b = bid >> 5;
  const int hw0 = (bid & 31) << 7;
  const int q = tid >> 5, slot = tid & 31;
  const int lane = tid & 63, wv = tid >> 6;

  const float* xbase = x + ((size_t)b * 128) * 4096 + hw0 + (slot << 2);
  float4 xv[8];
#pragma unroll
  for (int p = 0; p < 8; ++p)
    xv[p] = *(const float4*)(xbase + (size_t)(q * 8 + p) * 4096);

  float s1[4] = {0.f, 0.f, 0.f, 0.f}, s2[4] = {0.f, 0.f, 0.f, 0.f};
#pragma unroll
  for (int p = 0; p < 8; ++p) {
    s1[0] += xv[p].x; s2[0] = fmaf(xv[p].x, xv[p].x, s2[0]);
    s1[1] += xv[p].y; s2[1] = fmaf(xv[p].y, xv[p].y, s2[1]);
    s1[2] += xv[p].z; s2[2] = fmaf(xv[p].z, xv[p].z, s2[2]);
    s1[3] += xv[p].w; s2[3] = fmaf(xv[p].w, xv[p].w, s2[3]);
  }
#pragma unroll
  for (int j = 0; j < 4; ++j) {
    s1[j] += __shfl_xor(s1[j], 32);
    s2[j] += __shfl_xor(s2[j], 32);
  }
  if (lane < 32) {
    float* psp = (float*)(slds + (wv * 32 + slot) * 36);
#pragma unroll
    for (int j = 0; j < 4; ++j) { psp[j] = s1[j]; psp[4 + j] = s2[j]; }
  }
  __syncthreads();
  if (tid < 128) {
    const int sl2 = tid >> 2, j2 = tid & 3;
    float a1 = 0.f, a2 = 0.f;
#pragma unroll
    for (int w = 0; w < 8; ++w) {
      const float* psp = (const float*)(slds + (w * 32 + sl2) * 36);
      a1 += psp[j2]; a2 += psp[4 + j2];
    }
    const float mu = a1 * 0.0078125f;
    const float var = a2 * 0.0078125f - mu * mu;
    mu_s[tid] = mu;
    rs_s[tid] = rsqrtf(var + 1e-5f);
  }
  __syncthreads();

  float lgv[8], lbv[8];
#pragma unroll
  for (int p = 0; p < 8; ++p) { lgv[p] = lg[q * 8 + p]; lbv[p] = lb[q * 8 + p]; }
#pragma unroll
  for (int j = 0; j < 4; ++j) {
    const int pos = (slot << 2) + j;
    const float mu = mu_s[pos], rs = rs_s[pos];
    float y[8];
#pragma unroll
    for (int p = 0; p < 8; ++p) {
      const float xvj = j == 0 ? xv[p].x : j == 1 ? xv[p].y : j == 2 ? xv[p].z : xv[p].w;
      y[p] = (xvj - mu) * rs * lgv[p] + lbv[p];
    }
    unsigned h0, h1, h2, h3;
    asm("v_cvt_pk_bf16_f32 %0, %1, %2" : "=v"(h0) : "v"(y[0]), "v"(y[1]));
    asm("v_cvt_pk_bf16_f32 %0, %1, %2" : "=v"(h1) : "v"(y[2]), "v"(y[3]));
    asm("v_cvt_pk_bf16_f32 %0, %1, %2" : "=v"(h2) : "v"(y[4]), "v"(y[5]));
    asm("v_cvt_pk_bf16_f32 %0, %1, %2" : "=v"(h3) : "v"(y[6]), "v"(y[7]));
    uint4 v; v.x = h0; v.y = h1; v.z = h2; v.w = h3;
    *(uint4*)(slds + pos * 272 + (q << 4)) = v;
  }
  __syncthreads();
#pragma unroll
  for (int it = 0; it < 4; ++it) {
    const int idx = (it << 9) + tid;
    const int row = idx >> 4, g = idx & 15;
    uint4 v = *(const uint4*)(slds + row * 272 + (g << 4));
    *(uint4*)((unsigned char*)xn + ((size_t)(b * 4096 + hw0 + row)) * 256 + (g << 4)) = v;
  }
}

// ---------------- Persistent bidirectional GRU scan ----------------
// 4-wave blocks (256 thr), 16 sequences; each wave owns 32 gate-cols as two
// 16-col MFMA sub-blocks (A and B). Weights = 48 bf16x8/wave -> AGPRs at
// 1 wave/SIMD (launch_bounds(256,1): full 512-reg unified budget).
// LDS B-operand reads halve (32 b128/CU/step); one wave owns 48 MFMAs + all
// gate math so VALU hides under the MFMA pipe. Structure otherwise = r7.
__global__ __launch_bounds__(256, 1) void scan_kernel(
    const unsigned short* __restrict__ xn, unsigned short* __restrict__ cat,
    const float* __restrict__ wih0, const float* __restrict__ whh0,
    const float* __restrict__ bih0, const float* __restrict__ bhh0,
    const float* __restrict__ wih1, const float* __restrict__ whh1,
    const float* __restrict__ bih1, const float* __restrict__ bhh1,
    const float* __restrict__ wih2, const float* __restrict__ whh2,
    const float* __restrict__ bih2, const float* __restrict__ bhh2,
    const float* __restrict__ wih3, const float* __restrict__ whh3,
    const float* __restrict__ bih3, const float* __restrict__ bhh3) {
  __shared__ __align__(16) unsigned char lds[16384];
  const int tid = threadIdx.x;
  const int bid = blockIdx.x;
  const int dir = bid >> 6;
  const int grp = bid & 63;
  const int fwd = !(dir & 1);
  const int vert = dir >> 1;
  const int b = grp >> 2;
  const int r0 = (grp & 3) << 4;
  const int wv = tid >> 6;
  const int lane = tid & 63;
  const int l15 = lane & 15;
  const int l4 = lane >> 4;

  const float* wih = dir == 0 ? wih0 : dir == 1 ? wih1 : dir == 2 ? wih2 : wih3;
  const float* whh = dir == 0 ? whh0 : dir == 1 ? whh1 : dir == 2 ? whh2 : whh3;
  const float* bih = dir == 0 ? bih0 : dir == 1 ? bih1 : dir == 2 ? bih2 : bih3;
  const float* bhh = dir == 0 ? bhh0 : dir == 1 ? bhh1 : dir == 2 ? bhh2 : bhh3;

  // Two 16-col sub-blocks per wave: m-rows caA = wv*32 + l15, caB = caA + 16.
  const int caA = (wv << 5) + l15;
  bf16x8 wfA[3][2][4], wfB[3][2][4];
#pragma unroll
  for (int g = 0; g < 3; ++g) {
    const float sc = g == 2 ? N2LOG2E : NLOG2E;
#pragma unroll
    for (int s = 0; s < 2; ++s) {
      const float* Wp = s ? whh : wih;
#pragma unroll
      for (int kc = 0; kc < 4; ++kc) {
        wfA[g][s][kc] = pack8s(Wp + (size_t)((g << 7) + caA) * 128 + (kc << 5) + (l4 << 3), sc);
        wfB[g][s][kc] = pack8s(Wp + (size_t)((g << 7) + caA + 16) * 128 + (kc << 5) + (l4 << 3), sc);
      }
    }
  }
  const int cbA = (wv << 5) + (l4 << 2);
  const int cbB = cbA + 16;
  f32x4 brA, bzA, bnxA, bnhA, brB, bzB, bnxB, bnhB;
  {
    float4 a = *(const float4*)(bih + cbA), c = *(const float4*)(bhh + cbA);
    brA[0] = (a.x + c.x) * NLOG2E; brA[1] = (a.y + c.y) * NLOG2E;
    brA[2] = (a.z + c.z) * NLOG2E; brA[3] = (a.w + c.w) * NLOG2E;
    a = *(const float4*)(bih + cbB); c = *(const float4*)(bhh + cbB);
    brB[0] = (a.x + c.x) * NLOG2E; brB[1] = (a.y + c.y) * NLOG2E;
    brB[2] = (a.z + c.z) * NLOG2E; brB[3] = (a.w + c.w) * NLOG2E;
    a = *(const float4*)(bih + 128 + cbA); c = *(const float4*)(bhh + 128 + cbA);
    bzA[0] = (a.x + c.x) * NLOG2E; bzA[1] = (a.y + c.y) * NLOG2E;
    bzA[2] = (a.z + c.z) * NLOG2E; bzA[3] = (a.w + c.w) * NLOG2E;
    a = *(const float4*)(bih + 128 + cbB); c = *(const float4*)(bhh + 128 + cbB);
    bzB[0] = (a.x + c.x) * NLOG2E; bzB[1] = (a.y + c.y) * NLOG2E;
    bzB[2] = (a.z + c.z) * NLOG2E; bzB[3] = (a.w + c.w) * NLOG2E;
    a = *(const float4*)(bih + 256 + cbA);
    bnxA[0] = a.x * N2LOG2E; bnxA[1] = a.y * N2LOG2E;
    bnxA[2] = a.z * N2LOG2E; bnxA[3] = a.w * N2LOG2E;
    a = *(const float4*)(bih + 256 + cbB);
    bnxB[0] = a.x * N2LOG2E; bnxB[1] = a.y * N2LOG2E;
    bnxB[2] = a.z * N2LOG2E; bnxB[3] = a.w * N2LOG2E;
    c = *(const float4*)(bhh + 256 + cbA);
    bnhA[0] = c.x * N2LOG2E; bnhA[1] = c.y * N2LOG2E;
    bnhA[2] = c.z * N2LOG2E; bnhA[3] = c.w * N2LOG2E;
    c = *(const float4*)(bhh + 256 + cbB);
    bnhB[0] = c.x * N2LOG2E; bnhB[1] = c.y * N2LOG2E;
    bnhB[2] = c.z * N2LOG2E; bnhB[3] = c.w * N2LOG2E;
  }

  const int ss = tid >> 4, ck = tid & 15;
  const unsigned char* xsp =
      (const unsigned char*)xn +
      (vert ? ((size_t)b << 20) + (size_t)(r0 + ss) * 256 + (ck << 4)
            : ((size_t)(b * 64 + r0 + ss) << 14) + (ck << 4));
  const int xstep = vert ? 16384 : 256;
  const int sdst = (ss * 256 + (ck << 4)) ^ ((ss & 15) << 4);

  const int seq = r0 + l15;
  const int cstep = vert ? 65536 : 1024;
  unsigned char* catp =
      (unsigned char*)cat +
      ((size_t)b * 4096 + (size_t)(vert ? seq : seq * 64)) * 1024 + dir * 256 + (cbA << 1) +
      (size_t)(fwd ? 0 : 63) * cstep;
  const int cdelta = fwd ? cstep : -cstep;

  // zero hbufA (@8192, 4KB): 256 threads x 16B
  {
    uint4 z; z.x = 0; z.y = 0; z.z = 0; z.w = 0;
    *(uint4*)(lds + 8192 + tid * 16) = z;
  }
  f32x4 hsA = {0.f, 0.f, 0.f, 0.f}, hsB = {0.f, 0.f, 0.f, 0.f};

  uint4 sX, sY;
  f32x4 grPa, gzPa, gnxPa, grPb, gzPb, gnxPb;
  f32x4 grQa, gzQa, gnxQa, grQb, gzQb, gnxQb;
  {
    const unsigned char* xlq =
        (const unsigned char*)xn +
        (vert ? ((size_t)b << 20) + (size_t)(fwd ? 0 : 63) * 16384 + (size_t)seq * 256
              : ((size_t)(b * 64 + seq) << 14) + (size_t)(fwd ? 0 : 63) * 256) +
        (l4 << 4);
    bf16x8 x0[4];
#pragma unroll
    for (int kc = 0; kc < 4; ++kc) x0[kc] = *(const bf16x8*)(xlq + (kc << 6));
    uint4 s1v;
    s1v = *(const uint4*)(xsp + (fwd ? 1 : 62) * xstep);
    sX = *(const uint4*)(xsp + (fwd ? 2 : 61) * xstep);
    grPa = brA; gzPa = bzA; gnxPa = bnxA;
    grPb = brB; gzPb = bzB; gnxPb = bnxB;
#pragma unroll
    for (int kc = 0; kc < 4; ++kc) {
      grPa = __builtin_amdgcn_mfma_f32_16x16x32_bf16(wfA[0][0][kc], x0[kc], grPa, 0, 0, 0);
      grPb = __builtin_amdgcn_mfma_f32_16x16x32_bf16(wfB[0][0][kc], x0[kc], grPb, 0, 0, 0);
      gzPa = __builtin_amdgcn_mfma_f32_16x16x32_bf16(wfA[1][0][kc], x0[kc], gzPa, 0, 0, 0);
      gzPb = __builtin_amdgcn_mfma_f32_16x16x32_bf16(wfB[1][0][kc], x0[kc], gzPb, 0, 0, 0);
      gnxPa = __builtin_amdgcn_mfma_f32_16x16x32_bf16(wfA[2][0][kc], x0[kc], gnxPa, 0, 0, 0);
      gnxPb = __builtin_amdgcn_mfma_f32_16x16x32_bf16(wfB[2][0][kc], x0[kc], gnxPb, 0, 0, 0);
    }
    *(uint4*)(lds + 4096 + sdst) = s1v;
  }
  __syncthreads();

#define GATEBLK(GRC, GZC, GNXC, RH, ZH, NH, HS, HP0, HP1)                       \
    f32x4 hnew_;                                                                \
    _Pragma("unroll")                                                           \
    for (int r = 0; r < 4; ++r) {                                               \
      const float er = __builtin_amdgcn_exp2f(GRC[r] + RH[r]);                  \
      const float rr = __builtin_amdgcn_rcpf(1.f + er);                         \
      const float ez = __builtin_amdgcn_exp2f(GZC[r] + ZH[r]);                  \
      const float zz = __builtin_amdgcn_rcpf(1.f + ez);                         \
      const float pre = GNXC[r] + rr * NH[r];                                   \
      const float e2 = __builtin_amdgcn_exp2f(pre);                             \
      const float nn = fmaf(2.f, __builtin_amdgcn_rcpf(1.f + e2), -1.f);        \
      hnew_[r] = nn + zz * (HS[r] - nn);                                        \
    }                                                                           \
    HS = hnew_;                                                                 \
    asm("v_cvt_pk_bf16_f32 %0, %1, %2" : "=v"(HP0) : "v"(hnew_[0]), "v"(hnew_[1])); \
    asm("v_cvt_pk_bf16_f32 %0, %1, %2" : "=v"(HP1) : "v"(hnew_[2]), "v"(hnew_[3]));

#define STEP(TT, HCUR, HNXT, XRD, XWR, XW, XL,                                  \
             GRCa, GZCa, GNXCa, GRCb, GZCb, GNXCb,                              \
             GRNa, GZNa, GNXNa, GRNb, GZNb, GNXNb)                              \
  {                                                                             \
    bf16x8 ha[4], xa[4];                                                        \
    _Pragma("unroll")                                                           \
    for (int kc = 0; kc < 4; ++kc) {                                            \
      const int base = (l15 * 256 + (kc << 6) + (l4 << 4)) ^ (l15 << 4);        \
      ha[kc] = *(const bf16x8*)(lds + (HCUR) + base);                           \
      xa[kc] = *(const bf16x8*)(lds + (XRD) + base);                            \
    }                                                                           \
    *(uint4*)(lds + (XWR) + sdst) = XW;                                         \
    {                                                                           \
      const int tl = (TT) + 3 > 63 ? 63 : (TT) + 3;                             \
      XL = *(const uint4*)(xsp + (fwd ? tl : 63 - tl) * xstep);                 \
    }                                                                           \
    /* h chains: six independent depth-4 (critical) */                          \
    f32x4 rha = {0.f, 0.f, 0.f, 0.f}, zha = {0.f, 0.f, 0.f, 0.f}, nha = bnhA;   \
    f32x4 rhb = {0.f, 0.f, 0.f, 0.f}, zhb = {0.f, 0.f, 0.f, 0.f}, nhb = bnhB;   \
    _Pragma("unroll")                                                           \
    for (int kc = 0; kc < 4; ++kc) {                                            \
      rha = __builtin_amdgcn_mfma_f32_16x16x32_bf16(wfA[0][1][kc], ha[kc], rha, 0, 0, 0); \
      rhb = __builtin_amdgcn_mfma_f32_16x16x32_bf16(wfB[0][1][kc], ha[kc], rhb, 0, 0, 0); \
      zha = __builtin_amdgcn_mfma_f32_16x16x32_bf16(wfA[1][1][kc], ha[kc], zha, 0, 0, 0); \
      zhb = __builtin_amdgcn_mfma_f32_16x16x32_bf16(wfB[1][1][kc], ha[kc], zhb, 0, 0, 0); \
      nha = __builtin_amdgcn_mfma_f32_16x16x32_bf16(wfA[2][1][kc], ha[kc], nha, 0, 0, 0); \
      nhb = __builtin_amdgcn_mfma_f32_16x16x32_bf16(wfB[2][1][kc], ha[kc], nhb, 0, 0, 0); \
    }                                                                           \
    /* x-gate look-ahead for step TT+1 */                                       \
    GRNa = brA; GZNa = bzA; GNXNa = bnxA;                                       \
    GRNb = brB; GZNb = bzB; GNXNb = bnxB;                                       \
    _Pragma("unroll")                                                           \
    for (int kc = 0; kc < 4; ++kc) {                                            \
      GRNa = __builtin_amdgcn_mfma_f32_16x16x32_bf16(wfA[0][0][kc], xa[kc], GRNa, 0, 0, 0); \
      GRNb = __builtin_amdgcn_mfma_f32_16x16x32_bf16(wfB[0][0][kc], xa[kc], GRNb, 0, 0, 0); \
      GZNa = __builtin_amdgcn_mfma_f32_16x16x32_bf16(wfA[1][0][kc], xa[kc], GZNa, 0, 0, 0); \
      GZNb = __builtin_amdgcn_mfma_f32_16x16x32_bf16(wfB[1][0][kc], xa[kc], GZNb, 0, 0, 0); \
      GNXNa = __builtin_amdgcn_mfma_f32_16x16x32_bf16(wfA[2][0][kc], xa[kc], GNXNa, 0, 0, 0); \
      GNXNb = __builtin_amdgcn_mfma_f32_16x16x32_bf16(wfB[2][0][kc], xa[kc], GNXNb, 0, 0, 0); \
    }                                                                           \
    unsigned hpa0, hpa1, hpb0, hpb1;                                            \
    { GATEBLK(GRCa, GZCa, GNXCa, rha, zha, nha, hsA, hpa0, hpa1) }              \
    { GATEBLK(GRCb, GZCb, GNXCb, rhb, zhb, nhb, hsB, hpb0, hpb1) }              \
    {                                                                           \
      unsigned long long hpA = (unsigned long long)hpa0 | ((unsigned long long)hpa1 << 32); \
      unsigned long long hpB = (unsigned long long)hpb0 | ((unsigned long long)hpb1 << 32); \
      *(unsigned long long*)(lds + (HNXT) + ((l15 * 256 + (cbA << 1)) ^ (l15 << 4))) = hpA; \
      *(unsigned long long*)(lds + (HNXT) + ((l15 * 256 + (cbB << 1)) ^ (l15 << 4))) = hpB; \
    }                                                                           \
    {                                                                           \
      uint2 va; va.x = hpa0; va.y = hpa1;                                       \
      uint2 vb; vb.x = hpb0; vb.y = hpb1;                                       \
      *(uint2*)catp = va;                                                       \
      *(uint2*)(catp + 32) = vb;                                                \
      catp += cdelta;                                                           \
    }                                                                           \
    asm volatile("s_waitcnt lgkmcnt(0)" ::: "memory");                          \
    __builtin_amdgcn_s_barrier();                                               \
    asm volatile("" ::: "memory");                                              \
  }

  for (int tt2 = 0; tt2 < 64; tt2 += 2) {
    STEP(tt2, 8192, 12288, 4096, 0, sX, sY,
         grPa, gzPa, gnxPa, grPb, gzPb, gnxPb,
         grQa, gzQa, gnxQa, grQb, gzQb, gnxQb);
    STEP(tt2 + 1, 12288, 8192, 0, 4096, sY, sX,
         grQa, gzQa, gnxQa, grQb, gzQb, gnxQb,
         grPa, gzPa, gnxPa, grPb, gzPb, gnxPb);
  }
#undef STEP
#undef GATEBLK
}

// ---------------- Projection: out = cat[65536,512] @ pwb^T + pb + x ----------------
__global__ __launch_bounds__(512, 4) void proj_kernel(
    const unsigned short* __restrict__ cat, const unsigned short* __restrict__ pwb,
    const float* __restrict__ pb, const float* __restrict__ x,
    float* __restrict__ out) {
  __shared__ __align__(16) unsigned char lds[33280];
  const int tid = threadIdx.x;
  const int bid = blockIdx.x;
  const int row0 = bid << 6;
  const int b = row0 >> 12;
  const int hw0 = row0 & 4095;
  const int wv = tid >> 6, lane = tid & 63, l15 = lane & 15, l4 = lane >> 4;

  const int cc = (wv << 4) + l15;
  bf16x8 wfr[16];
#pragma unroll
  for (int kc = 0; kc < 16; ++kc)
    wfr[kc] = *(const bf16x8*)(pwb + (size_t)cc * 512 + (kc << 5) + (l4 << 3));
  const float pbv = pb[cc];

  f32x4 acc[4];
#pragma unroll
  for (int mt = 0; mt < 4; ++mt) acc[mt] = {pbv, pbv, pbv, pbv};

#pragma unroll
  for (int s = 0; s < 2; ++s) {
#pragma unroll
    for (int it = 0; it < 4; ++it) {
      const int item = tid + (it << 9);
      const int rr = item >> 6, ckk = item & 63;
      uint4 v = *(const uint4*)((const unsigned char*)cat +
                                ((size_t)(row0 + (s << 5) + rr)) * 1024 + ckk * 16);
      *(uint4*)(lds + rr * 1024 + ((ckk ^ (rr & 7)) << 4)) = v;
    }
    __syncthreads();
#pragma unroll
    for (int mh = 0; mh < 2; ++mh) {
      const int mt = (s << 1) + mh;
      const int rl = (mh << 4) + l15;
#pragma unroll
      for (int kc = 0; kc < 16; ++kc) {
        bf16x8 af =
            *(const bf16x8*)(lds + rl * 1024 + ((((kc << 2) + l4) ^ (rl & 7)) << 4));
        acc[mt] = __builtin_amdgcn_mfma_f32_16x16x32_bf16(af, wfr[kc], acc[mt], 0, 0, 0);
      }
    }
    __syncthreads();
  }

#pragma unroll
  for (int mt = 0; mt < 4; ++mt)
#pragma unroll
    for (int j = 0; j < 4; ++j)
      *(float*)(lds + cc * 260 + (((mt << 4) + (l4 << 2) + j) << 2)) = acc[mt][j];
  __syncthreads();
#pragma unroll
  for (int it = 0; it < 16; ++it) {
    const int c = (wv << 4) + it;
    const float v = *(const float*)(lds + c * 260 + (lane << 2));
    const size_t off = (size_t)(b * 128 + c) * 4096 + hw0 + lane;
    out[off] = v + x[off];
  }
}

extern "C" void kernel_launch(void* const* d_in, const int* in_sizes, int n_in,
                              void* d_out, int out_size, void* d_ws, size_t ws_size,
                              hipStream_t stream) {
  const float* x = (const float*)d_in[0];
  const float* lg = (const float*)d_in[1];
  const float* lb = (const float*)d_in[2];
  unsigned short* xn = (unsigned short*)d_ws;                       // 16.8 MB
  unsigned short* cat =
      (unsigned short*)((unsigned char*)d_ws + 16777216);           // 67.1 MB
  unsigned short* pwb =
      (unsigned short*)((unsigned char*)d_ws + 16777216 + 67108864);  // 128 KB

  pwprep_kernel<<<128, 512, 0, stream>>>((const float*)d_in[19], pwb);
  ln_kernel<<<512, 512, 0, stream>>>(x, lg, lb, xn);
  scan_kernel<<<256, 256, 0, stream>>>(
      xn, cat,
      (const float*)d_in[3], (const float*)d_in[4], (const float*)d_in[5], (const float*)d_in[6],
      (const float*)d_in[7], (const float*)d_in[8], (const float*)d_in[9], (const float*)d_in[10],
      (const float*)d_in[11], (const float*)d_in[12], (const float*)d_in[13], (const float*)d_in[14],
      (const float*)d_in[15], (const float*)d_in[16], (const float*)d_in[17], (const float*)d_in[18]);
  proj_kernel<<<1024, 512, 0, stream>>>(cat, pwb, (const float*)d_in[20], x,
                                        (float*)d_out);
}

// Round 12
// 119.055 us; speedup vs baseline: 1.0652x; 1.0652x over previous
//
#include <hip/hip_runtime.h>

typedef short bf16x8 __attribute__((ext_vector_type(8)));
typedef float f32x4 __attribute__((ext_vector_type(4)));

static __device__ __forceinline__ unsigned short f2bf(float f) {
  unsigned u = __builtin_bit_cast(unsigned, f);
  u += 0x7FFFu + ((u >> 16) & 1u);   // round-nearest-even to bf16
  return (unsigned short)(u >> 16);
}

static __device__ __forceinline__ bf16x8 pack8s(const float* p, float s) {
  float4 a = *(const float4*)p;
  float4 b = *(const float4*)(p + 4);
  bf16x8 r;
  r[0] = (short)f2bf(a.x * s); r[1] = (short)f2bf(a.y * s);
  r[2] = (short)f2bf(a.z * s); r[3] = (short)f2bf(a.w * s);
  r[4] = (short)f2bf(b.x * s); r[5] = (short)f2bf(b.y * s);
  r[6] = (short)f2bf(b.z * s); r[7] = (short)f2bf(b.w * s);
  return r;
}

#define NLOG2E -1.442695040888963f
#define N2LOG2E -2.885390081777927f

// ---------------- pw f32[128][512] -> bf16 (one-time) ----------------
__global__ __launch_bounds__(512) void pwprep_kernel(
    const float* __restrict__ pw, unsigned short* __restrict__ pwb) {
  const int i = blockIdx.x * 512 + threadIdx.x;
  pwb[i] = f2bf(pw[i]);
}

// ---------------- LayerNorm: x[B,C,H,W] f32 -> xn[B,HW,C] bf16 ----------------
__global__ __launch_bounds__(512, 2) void ln_kernel(
    const float* __restrict__ x, const float* __restrict__ lg,
    const float* __restrict__ lb, unsigned short* __restrict__ xn) {
  __shared__ __align__(16) unsigned char slds[35840];
  float* mu_s = (float*)(slds + 34816);
  float* rs_s = (float*)(slds + 35328);
  const int tid = threadIdx.x;
  const int bid = blockIdx.x;
  const int b = bid >> 5;
  const int hw0 = (bid & 31) << 7;
  const int q = tid >> 5, slot = tid & 31;
  const int lane = tid & 63, wv = tid >> 6;

  const float* xbase = x + ((size_t)b * 128) * 4096 + hw0 + (slot << 2);
  float4 xv[8];
#pragma unroll
  for (int p = 0; p < 8; ++p)
    xv[p] = *(const float4*)(xbase + (size_t)(q * 8 + p) * 4096);

  float s1[4] = {0.f, 0.f, 0.f, 0.f}, s2[4] = {0.f, 0.f, 0.f, 0.f};
#pragma unroll
  for (int p = 0; p < 8; ++p) {
    s1[0] += xv[p].x; s2[0] = fmaf(xv[p].x, xv[p].x, s2[0]);
    s1[1] += xv[p].y; s2[1] = fmaf(xv[p].y, xv[p].y, s2[1]);
    s1[2] += xv[p].z; s2[2] = fmaf(xv[p].z, xv[p].z, s2[2]);
    s1[3] += xv[p].w; s2[3] = fmaf(xv[p].w, xv[p].w, s2[3]);
  }
#pragma unroll
  for (int j = 0; j < 4; ++j) {
    s1[j] += __shfl_xor(s1[j], 32);
    s2[j] += __shfl_xor(s2[j], 32);
  }
  if (lane < 32) {
    float* psp = (float*)(slds + (wv * 32 + slot) * 36);
#pragma unroll
    for (int j = 0; j < 4; ++j) { psp[j] = s1[j]; psp[4 + j] = s2[j]; }
  }
  __syncthreads();
  if (tid < 128) {
    const int sl2 = tid >> 2, j2 = tid & 3;
    float a1 = 0.f, a2 = 0.f;
#pragma unroll
    for (int w = 0; w < 8; ++w) {
      const float* psp = (const float*)(slds + (w * 32 + sl2) * 36);
      a1 += psp[j2]; a2 += psp[4 + j2];
    }
    const float mu = a1 * 0.0078125f;
    const float var = a2 * 0.0078125f - mu * mu;
    mu_s[tid] = mu;
    rs_s[tid] = rsqrtf(var + 1e-5f);
  }
  __syncthreads();

  float lgv[8], lbv[8];
#pragma unroll
  for (int p = 0; p < 8; ++p) { lgv[p] = lg[q * 8 + p]; lbv[p] = lb[q * 8 + p]; }
#pragma unroll
  for (int j = 0; j < 4; ++j) {
    const int pos = (slot << 2) + j;
    const float mu = mu_s[pos], rs = rs_s[pos];
    float y[8];
#pragma unroll
    for (int p = 0; p < 8; ++p) {
      const float xvj = j == 0 ? xv[p].x : j == 1 ? xv[p].y : j == 2 ? xv[p].z : xv[p].w;
      y[p] = (xvj - mu) * rs * lgv[p] + lbv[p];
    }
    unsigned h0, h1, h2, h3;
    asm("v_cvt_pk_bf16_f32 %0, %1, %2" : "=v"(h0) : "v"(y[0]), "v"(y[1]));
    asm("v_cvt_pk_bf16_f32 %0, %1, %2" : "=v"(h1) : "v"(y[2]), "v"(y[3]));
    asm("v_cvt_pk_bf16_f32 %0, %1, %2" : "=v"(h2) : "v"(y[4]), "v"(y[5]));
    asm("v_cvt_pk_bf16_f32 %0, %1, %2" : "=v"(h3) : "v"(y[6]), "v"(y[7]));
    uint4 v; v.x = h0; v.y = h1; v.z = h2; v.w = h3;
    *(uint4*)(slds + pos * 272 + (q << 4)) = v;
  }
  __syncthreads();
#pragma unroll
  for (int it = 0; it < 4; ++it) {
    const int idx = (it << 9) + tid;
    const int row = idx >> 4, g = idx & 15;
    uint4 v = *(const uint4*)(slds + row * 272 + (g << 4));
    *(uint4*)((unsigned char*)xn + ((size_t)(b * 4096 + hw0 + row)) * 256 + (g << 4)) = v;
  }
}

// ---------------- Persistent bidirectional GRU scan ----------------
// Round-10 structure (8 waves, measured best 71.6 µs) + sched_group_barrier
// interleave: emitted order {8 ds_read} -> {12 h-MFMA} -> 6x{2 x-MFMA, 10
// VALU} so gate math issues while the independent x-look-ahead MFMAs drain
// the matrix pipe (breaks the in-order-issue phase serialization).
__global__ __launch_bounds__(512, 2) void scan_kernel(
    const unsigned short* __restrict__ xn, unsigned short* __restrict__ cat,
    const float* __restrict__ wih0, const float* __restrict__ whh0,
    const float* __restrict__ bih0, const float* __restrict__ bhh0,
    const float* __restrict__ wih1, const float* __restrict__ whh1,
    const float* __restrict__ bih1, const float* __restrict__ bhh1,
    const float* __restrict__ wih2, const float* __restrict__ whh2,
    const float* __restrict__ bih2, const float* __restrict__ bhh2,
    const float* __restrict__ wih3, const float* __restrict__ whh3,
    const float* __restrict__ bih3, const float* __restrict__ bhh3) {
  __shared__ __align__(16) unsigned char lds[16384];
  const int tid = threadIdx.x;
  const int bid = blockIdx.x;
  const int dir = bid >> 6;
  const int grp = bid & 63;
  const int fwd = !(dir & 1);
  const int vert = dir >> 1;
  const int b = grp >> 2;
  const int r0 = (grp & 3) << 4;
  const int wv = tid >> 6;
  const int lane = tid & 63;
  const int l15 = lane & 15;
  const int l4 = lane >> 4;

  const float* wih = dir == 0 ? wih0 : dir == 1 ? wih1 : dir == 2 ? wih2 : wih3;
  const float* whh = dir == 0 ? whh0 : dir == 1 ? whh1 : dir == 2 ? whh2 : whh3;
  const float* bih = dir == 0 ? bih0 : dir == 1 ? bih1 : dir == 2 ? bih2 : bih3;
  const float* bhh = dir == 0 ? bhh0 : dir == 1 ? bhh1 : dir == 2 ? bhh2 : bhh3;

  const int ca = (wv << 4) + l15;
  bf16x8 wf[3][2][4];
#pragma unroll
  for (int g = 0; g < 3; ++g) {
    const float sc = g == 2 ? N2LOG2E : NLOG2E;
#pragma unroll
    for (int s = 0; s < 2; ++s) {
      const float* Wp = s ? whh : wih;
#pragma unroll
      for (int kc = 0; kc < 4; ++kc)
        wf[g][s][kc] = pack8s(Wp + (size_t)((g << 7) + ca) * 128 + (kc << 5) + (l4 << 3), sc);
    }
  }
  const int cb = (wv << 4) + (l4 << 2);
  f32x4 br4, bz4, bnx4, bnh4;
  {
    float4 a = *(const float4*)(bih + cb), b2 = *(const float4*)(bhh + cb);
    br4[0] = (a.x + b2.x) * NLOG2E; br4[1] = (a.y + b2.y) * NLOG2E;
    br4[2] = (a.z + b2.z) * NLOG2E; br4[3] = (a.w + b2.w) * NLOG2E;
    a = *(const float4*)(bih + 128 + cb); b2 = *(const float4*)(bhh + 128 + cb);
    bz4[0] = (a.x + b2.x) * NLOG2E; bz4[1] = (a.y + b2.y) * NLOG2E;
    bz4[2] = (a.z + b2.z) * NLOG2E; bz4[3] = (a.w + b2.w) * NLOG2E;
    a = *(const float4*)(bih + 256 + cb);
    bnx4[0] = a.x * N2LOG2E; bnx4[1] = a.y * N2LOG2E;
    bnx4[2] = a.z * N2LOG2E; bnx4[3] = a.w * N2LOG2E;
    b2 = *(const float4*)(bhh + 256 + cb);
    bnh4[0] = b2.x * N2LOG2E; bnh4[1] = b2.y * N2LOG2E;
    bnh4[2] = b2.z * N2LOG2E; bnh4[3] = b2.w * N2LOG2E;
  }

  const int ss = tid >> 4, ck = tid & 15;
  const unsigned char* xsp =
      (const unsigned char*)xn +
      (vert ? ((size_t)b << 20) + (size_t)(r0 + ss) * 256 + (ck << 4)
            : ((size_t)(b * 64 + r0 + ss) << 14) + (ck << 4));
  const int xstep = vert ? 16384 : 256;
  const int sdst = (ss * 256 + (ck << 4)) ^ ((ss & 15) << 4);

  const int seq = r0 + l15;
  const int cstep = vert ? 65536 : 1024;
  unsigned char* catp =
      (unsigned char*)cat +
      ((size_t)b * 4096 + (size_t)(vert ? seq : seq * 64)) * 1024 + dir * 256 + (cb << 1) +
      (size_t)(fwd ? 0 : 63) * cstep;
  const int cdelta = fwd ? cstep : -cstep;

  *(unsigned long long*)(lds + 8192 + tid * 8) = 0ull;
  f32x4 hst = {0.f, 0.f, 0.f, 0.f};

  uint4 sX, sY;
  f32x4 grA, gzA, gnxA, grB, gzB, gnxB;
  {
    const unsigned char* xlq =
        (const unsigned char*)xn +
        (vert ? ((size_t)b << 20) + (size_t)(fwd ? 0 : 63) * 16384 + (size_t)seq * 256
              : ((size_t)(b * 64 + seq) << 14) + (size_t)(fwd ? 0 : 63) * 256) +
        (l4 << 4);
    bf16x8 x0[4];
#pragma unroll
    for (int kc = 0; kc < 4; ++kc) x0[kc] = *(const bf16x8*)(xlq + (kc << 6));
    uint4 s1v;
    if (tid < 256) {
      s1v = *(const uint4*)(xsp + (fwd ? 1 : 62) * xstep);
      sX = *(const uint4*)(xsp + (fwd ? 2 : 61) * xstep);
    }
    grA = br4; gzA = bz4; gnxA = bnx4;
#pragma unroll
    for (int kc = 0; kc < 4; ++kc) {
      grA = __builtin_amdgcn_mfma_f32_16x16x32_bf16(wf[0][0][kc], x0[kc], grA, 0, 0, 0);
      gzA = __builtin_amdgcn_mfma_f32_16x16x32_bf16(wf[1][0][kc], x0[kc], gzA, 0, 0, 0);
      gnxA = __builtin_amdgcn_mfma_f32_16x16x32_bf16(wf[2][0][kc], x0[kc], gnxA, 0, 0, 0);
    }
    if (tid < 256) *(uint4*)(lds + 4096 + sdst) = s1v;
  }
  __syncthreads();

#define STEP(TT, HCUR, HNXT, XRD, XWR, XW, XL, GRC, GZC, GNXC, GRN, GZN, GNXN)  \
  {                                                                             \
    bf16x8 ha[4], xa[4];                                                        \
    _Pragma("unroll")                                                           \
    for (int kc = 0; kc < 4; ++kc) {                                            \
      const int base = (l15 * 256 + (kc << 6) + (l4 << 4)) ^ (l15 << 4);        \
      ha[kc] = *(const bf16x8*)(lds + (HCUR) + base);                           \
      xa[kc] = *(const bf16x8*)(lds + (XRD) + base);                            \
    }                                                                           \
    if (tid < 256) {                                                            \
      *(uint4*)(lds + (XWR) + sdst) = XW;                                       \
      const int tl = (TT) + 3 > 63 ? 63 : (TT) + 3;                             \
      XL = *(const uint4*)(xsp + (fwd ? tl : 63 - tl) * xstep);                 \
    }                                                                           \
    f32x4 rh = {0.f, 0.f, 0.f, 0.f}, zh = {0.f, 0.f, 0.f, 0.f}, nh = bnh4;     \
    _Pragma("unroll")                                                           \
    for (int kc = 0; kc < 4; ++kc) {                                            \
      rh = __builtin_amdgcn_mfma_f32_16x16x32_bf16(wf[0][1][kc], ha[kc], rh, 0, 0, 0); \
      zh = __builtin_amdgcn_mfma_f32_16x16x32_bf16(wf[1][1][kc], ha[kc], zh, 0, 0, 0); \
      nh = __builtin_amdgcn_mfma_f32_16x16x32_bf16(wf[2][1][kc], ha[kc], nh, 0, 0, 0); \
    }                                                                           \
    GRN = br4; GZN = bz4; GNXN = bnx4;                                          \
    _Pragma("unroll")                                                           \
    for (int kc = 0; kc < 4; ++kc) {                                            \
      GRN = __builtin_amdgcn_mfma_f32_16x16x32_bf16(wf[0][0][kc], xa[kc], GRN, 0, 0, 0); \
      GZN = __builtin_amdgcn_mfma_f32_16x16x32_bf16(wf[1][0][kc], xa[kc], GZN, 0, 0, 0); \
      GNXN = __builtin_amdgcn_mfma_f32_16x16x32_bf16(wf[2][0][kc], xa[kc], GNXN, 0, 0, 0); \
    }                                                                           \
    f32x4 hnew;                                                                 \
    _Pragma("unroll")                                                           \
    for (int r = 0; r < 4; ++r) {                                               \
      const float er = __builtin_amdgcn_exp2f(GRC[r] + rh[r]);                  \
      const float rr = __builtin_amdgcn_rcpf(1.f + er);                         \
      const float ez = __builtin_amdgcn_exp2f(GZC[r] + zh[r]);                  \
      const float zz = __builtin_amdgcn_rcpf(1.f + ez);                         \
      const float pre = GNXC[r] + rr * nh[r];                                   \
      const float e2 = __builtin_amdgcn_exp2f(pre);                             \
      const float nn = fmaf(2.f, __builtin_amdgcn_rcpf(1.f + e2), -1.f);        \
      hnew[r] = nn + zz * (hst[r] - nn);                                        \
    }                                                                           \
    hst = hnew;                                                                 \
    unsigned hp0, hp1;                                                          \
    asm("v_cvt_pk_bf16_f32 %0, %1, %2" : "=v"(hp0) : "v"(hnew[0]), "v"(hnew[1])); \
    asm("v_cvt_pk_bf16_f32 %0, %1, %2" : "=v"(hp1) : "v"(hnew[2]), "v"(hnew[3])); \
    /* T19 directive list: ds_reads, h-MFMA block, then x-MFMA/VALU interleave */ \
    __builtin_amdgcn_sched_group_barrier(0x100, 8, 0);                          \
    __builtin_amdgcn_sched_group_barrier(0x008, 12, 0);                         \
    __builtin_amdgcn_sched_group_barrier(0x008, 2, 0);                          \
    __builtin_amdgcn_sched_group_barrier(0x002, 10, 0);                         \
    __builtin_amdgcn_sched_group_barrier(0x008, 2, 0);                          \
    __builtin_amdgcn_sched_group_barrier(0x002, 10, 0);                         \
    __builtin_amdgcn_sched_group_barrier(0x008, 2, 0);                          \
    __builtin_amdgcn_sched_group_barrier(0x002, 10, 0);                         \
    __builtin_amdgcn_sched_group_barrier(0x008, 2, 0);                          \
    __builtin_amdgcn_sched_group_barrier(0x002, 10, 0);                         \
    __builtin_amdgcn_sched_group_barrier(0x008, 2, 0);                          \
    __builtin_amdgcn_sched_group_barrier(0x002, 10, 0);                         \
    __builtin_amdgcn_sched_group_barrier(0x008, 2, 0);                          \
    __builtin_amdgcn_sched_group_barrier(0x002, 10, 0);                         \
    {                                                                           \
      unsigned long long hp = (unsigned long long)hp0 | ((unsigned long long)hp1 << 32); \
      *(unsigned long long*)(lds + (HNXT) + ((l15 * 256 + (cb << 1)) ^ (l15 << 4))) = hp; \
    }                                                                           \
    {                                                                           \
      uint2 v; v.x = hp0; v.y = hp1;                                            \
      *(uint2*)catp = v;                                                        \
      catp += cdelta;                                                           \
    }                                                                           \
    asm volatile("s_waitcnt lgkmcnt(0)" ::: "memory");                          \
    __builtin_amdgcn_s_barrier();                                               \
    asm volatile("" ::: "memory");                                              \
  }

  for (int tt2 = 0; tt2 < 64; tt2 += 2) {
    STEP(tt2, 8192, 12288, 4096, 0, sX, sY, grA, gzA, gnxA, grB, gzB, gnxB);
    STEP(tt2 + 1, 12288, 8192, 0, 4096, sY, sX, grB, gzB, gnxB, grA, gzA, gnxA);
  }
#undef STEP
}

// ---------------- Projection: out = cat[65536,512] @ pwb^T + pb + x ----------------
__global__ __launch_bounds__(512, 4) void proj_kernel(
    const unsigned short* __restrict__ cat, const unsigned short* __restrict__ pwb,
    const float* __restrict__ pb, const float* __restrict__ x,
    float* __restrict__ out) {
  __shared__ __align__(16) unsigned char lds[33280];
  const int tid = threadIdx.x;
  const int bid = blockIdx.x;
  const int row0 = bid << 6;
  const int b = row0 >> 12;
  const int hw0 = row0 & 4095;
  const int wv = tid >> 6, lane = tid & 63, l15 = lane & 15, l4 = lane >> 4;

  const int cc = (wv << 4) + l15;
  bf16x8 wfr[16];
#pragma unroll
  for (int kc = 0; kc < 16; ++kc)
    wfr[kc] = *(const bf16x8*)(pwb + (size_t)cc * 512 + (kc << 5) + (l4 << 3));
  const float pbv = pb[cc];

  f32x4 acc[4];
#pragma unroll
  for (int mt = 0; mt < 4; ++mt) acc[mt] = {pbv, pbv, pbv, pbv};

#pragma unroll
  for (int s = 0; s < 2; ++s) {
#pragma unroll
    for (int it = 0; it < 4; ++it) {
      const int item = tid + (it << 9);
      const int rr = item >> 6, ckk = item & 63;
      uint4 v = *(const uint4*)((const unsigned char*)cat +
                                ((size_t)(row0 + (s << 5) + rr)) * 1024 + ckk * 16);
      *(uint4*)(lds + rr * 1024 + ((ckk ^ (rr & 7)) << 4)) = v;
    }
    __syncthreads();
#pragma unroll
    for (int mh = 0; mh < 2; ++mh) {
      const int mt = (s << 1) + mh;
      const int rl = (mh << 4) + l15;
#pragma unroll
      for (int kc = 0; kc < 16; ++kc) {
        bf16x8 af =
            *(const bf16x8*)(lds + rl * 1024 + ((((kc << 2) + l4) ^ (rl & 7)) << 4));
        acc[mt] = __builtin_amdgcn_mfma_f32_16x16x32_bf16(af, wfr[kc], acc[mt], 0, 0, 0);
      }
    }
    __syncthreads();
  }

#pragma unroll
  for (int mt = 0; mt < 4; ++mt)
#pragma unroll
    for (int j = 0; j < 4; ++j)
      *(float*)(lds + cc * 260 + (((mt << 4) + (l4 << 2) + j) << 2)) = acc[mt][j];
  __syncthreads();
#pragma unroll
  for (int it = 0; it < 16; ++it) {
    const int c = (wv << 4) + it;
    const float v = *(const float*)(lds + c * 260 + (lane << 2));
    const size_t off = (size_t)(b * 128 + c) * 4096 + hw0 + lane;
    out[off] = v + x[off];
  }
}

extern "C" void kernel_launch(void* const* d_in, const int* in_sizes, int n_in,
                              void* d_out, int out_size, void* d_ws, size_t ws_size,
                              hipStream_t stream) {
  const float* x = (const float*)d_in[0];
  const float* lg = (const float*)d_in[1];
  const float* lb = (const float*)d_in[2];
  unsigned short* xn = (unsigned short*)d_ws;                       // 16.8 MB
  unsigned short* cat =
      (unsigned short*)((unsigned char*)d_ws + 16777216);           // 67.1 MB
  unsigned short* pwb =
      (unsigned short*)((unsigned char*)d_ws + 16777216 + 67108864);  // 128 KB

  pwprep_kernel<<<128, 512, 0, stream>>>((const float*)d_in[19], pwb);
  ln_kernel<<<512, 512, 0, stream>>>(x, lg, lb, xn);
  scan_kernel<<<256, 512, 0, stream>>>(
      xn, cat,
      (const float*)d_in[3], (const float*)d_in[4], (const float*)d_in[5], (const float*)d_in[6],
      (const float*)d_in[7], (const float*)d_in[8], (const float*)d_in[9], (const float*)d_in[10],
      (const float*)d_in[11], (const float*)d_in[12], (const float*)d_in[13], (const float*)d_in[14],
      (const float*)d_in[15], (const float*)d_in[16], (const float*)d_in[17], (const float*)d_in[18]);
  proj_kernel<<<1024, 512, 0, stream>>>(cat, pwb, (const float*)d_in[20], x,
                                        (float*)d_out);
}